// Round 1
// 4609.328 us; speedup vs baseline: 1.1626x; 1.1626x over previous
//
#include <hip/hip_runtime.h>
#include <cstdint>
#include <cstddef>

typedef unsigned short u16;
typedef unsigned long long u64;
typedef __attribute__((ext_vector_type(8))) short s16x8;
typedef __attribute__((ext_vector_type(4))) float f32x4;
typedef __attribute__((ext_vector_type(4))) unsigned short u16x4;

#define AGENT __HIP_MEMORY_SCOPE_AGENT

namespace {
constexpr int NWG  = 256;
constexpr int NTHR = 256;
constexpr int Bb   = 256;   // batch
constexpr int Tt   = 256;   // timesteps
constexpr int EMB_ = 256;
constexpr int HID_ = 512;
constexpr int NCLS = 32000;

// ---- LDS layout (bytes). B-operands stored in MFMA lane order:
//      elem addr = ((kb*NT + n)*64 + lane)*8 + e  -> ds_read_b128 lane-linear, 0 conflicts
constexpr int OFF_W1 = 0;                     // cell1 [24 kb][2 n][64 lane][8] = 49152 B
constexpr int OFF_W3 = 49152;                 // cell2, same shape
constexpr int OFF_W2 = 98304;                 // mix   [32 kb][1 n][64][8]     = 32768 B
constexpr int OFF_DS = 131072;                // gate scratch cell2 / generic [64][33] f32 = 8448 B
constexpr int OFF_DS1 = 139520;               // gate scratch cell1 (fused phase) = 8448 B
constexpr int OFF_C  = 147968;                // C  state [64][8] f32 (bq reuse in final)
constexpr int OFF_C1 = 150016;                // C1 state
constexpr int OFF_B1 = 152064;
constexpr int OFF_B3 = 152192;
constexpr int OFF_B2 = 152320;
constexpr int SMEM_BYTES = 152384;            // 1 WG/CU

// ---- workspace layout (bytes) ----
constexpr size_t WS_FL   = 0;                          // 256 WGs x 128 B = 32 KB
constexpr size_t WS_DONE = 32768;                      // 256 int done flags (one-time)
constexpr size_t WS_HB0  = 33792;                      // H parity buffers [B][512] bf16
constexpr size_t WS_HB1  = WS_HB0 + (size_t)Bb * HID_ * 2;
constexpr size_t WS_H1   = WS_HB1 + (size_t)Bb * HID_ * 2;   // H1 state
constexpr size_t WS_HM   = WS_H1 + (size_t)Bb * HID_ * 2;    // H1mix
constexpr size_t WS_XE   = WS_HM + (size_t)Bb * HID_ * 2;    // Xe [T][B][EMB] bf16
}  // namespace

struct Params {
  const int* X; const float* Hin; const float* Cin; const float* E;
  const float* Wx[4];  const float* Wh[4];  const float* bg[4];   // cell 1 (i,f,o,c)
  const float* Wx1[4]; const float* Wh1[4]; const float* bg1[4];  // cell 2
  const float* Wxh; const float* Whh; const float* bh;
  const float* Whq; const float* bq;
  float* out; char* ws;
};

__device__ __forceinline__ u16 f2bf(float f) {
  union { float f; unsigned u; } v; v.f = f;
  unsigned r = v.u + 0x7FFFu + ((v.u >> 16) & 1u);
  return (u16)(r >> 16);
}
__device__ __forceinline__ float sigm(float x) { return 1.f / (1.f + __expf(-x)); }
__device__ __forceinline__ float tanh_(float x) {
  x = fminf(fmaxf(x, -10.f), 10.f);
  float e = __expf(-2.f * x);
  return (1.f - e) / (1.f + e);
}
__device__ __forceinline__ f32x4 mfma16(s16x8 a, s16x8 b, f32x4 c) {
  return __builtin_amdgcn_mfma_f32_16x16x32_bf16(a, b, c, 0, 0, 0);
}

// ---- LLC-coherent (sc0 sc1) data movement: relaxed agent atomics bypass L1/L2
__device__ __forceinline__ void st8_llc(u16* p2, u64 v) {
  __hip_atomic_store((u64*)p2, v, __ATOMIC_RELAXED, AGENT);
}
__device__ __forceinline__ u64 ld8_llc(const u16* p2) {
  return __hip_atomic_load((const u64*)p2, __ATOMIC_RELAXED, AGENT);
}
__device__ __forceinline__ s16x8 ld16_llc(const u16* p2) {
  union { u64 q[2]; s16x8 v; } u;
  u.q[0] = ld8_llc(p2);
  u.q[1] = ld8_llc(p2 + 4);
  return u.v;
}

// Split barrier: arrive (after our stores drained) / waitbar (poll all 64 flags).
// __syncthreads drains vmcnt so all sc1 stores are LLC-acked before the flag.
__device__ __forceinline__ void arrive(int* fl, int slot, int ph) {
  __syncthreads();
  if (threadIdx.x == 0)
    __hip_atomic_store(&fl[slot * 32], ph, __ATOMIC_RELAXED, AGENT);
}
__device__ __forceinline__ void waitbar(int* fl, int ph) {
  if (threadIdx.x < 64) {
    for (;;) {
      int v = __hip_atomic_load(&fl[threadIdx.x * 32], __ATOMIC_RELAXED, AGENT);
      if (!__any(v < ph)) break;
      __builtin_amdgcn_s_sleep(1);
    }
  }
  __syncthreads();
  __builtin_amdgcn_fence(__ATOMIC_ACQUIRE, "workgroup");  // compiler/order barrier, cheap
}

// Heavy barrier (release store + agent acquire fence -> wbl2/inv). Used ONCE
// after init (publishes normal-stored Xe/H-init).
__device__ __forceinline__ void groupbar_heavy(int* fl, int slot, int ph) {
  __syncthreads();
  if (threadIdx.x == 0)
    __hip_atomic_store(&fl[slot * 32], ph, __ATOMIC_RELEASE, AGENT);
  if (threadIdx.x < 64) {
    for (;;) {
      int v = __hip_atomic_load(&fl[threadIdx.x * 32], __ATOMIC_RELAXED, AGENT);
      if (!__any(v < ph)) break;
      __builtin_amdgcn_s_sleep(1);
    }
  }
  __syncthreads();
  __builtin_amdgcn_fence(__ATOMIC_ACQUIRE, "agent");
}

// One-time all-grid done wait (before the final GEMM). Heavy on purpose: its
// acquire-inv lets the final GEMM use normal cached loads on H1b.
__device__ __forceinline__ void donebar(int* dn, int bi) {
  __syncthreads();
  if (threadIdx.x == 0)
    __hip_atomic_store(&dn[bi], 1, __ATOMIC_RELEASE, AGENT);
  for (;;) {
    int v = __hip_atomic_load(&dn[threadIdx.x], __ATOMIC_RELAXED, AGENT);
    if (!__any(v < 1)) break;
    __builtin_amdgcn_s_sleep(1);
  }
  __syncthreads();
  __builtin_amdgcn_fence(__ATOMIC_ACQUIRE, "agent");
}

// Single-cell phase (prologue cell1(0) and epilogue cell2(255)).
__device__ __forceinline__ void cell_phase(char* smem, int offW, int offB, int offC,
                                           const u16* Xt, const u16* Hrec, u16* Hdst,
                                           int g, int c, int w, int lane, int tid) {
  const int r = lane & 15, q = lane >> 4;
  const int row0 = w * 16;
  const u16* xrow = Xt + (size_t)(g * 64 + row0 + r) * EMB_;
  const u16* hrow = Hrec + (size_t)(g * 64 + row0 + r) * HID_;
  const u16* wb = (const u16*)(smem + offW) + lane * 8;
  f32x4 acc0 = {0.f, 0.f, 0.f, 0.f}, acc1 = {0.f, 0.f, 0.f, 0.f};
#pragma unroll
  for (int kb = 0; kb < 8; kb++) {                    // x_t part of K (256)
    s16x8 a  = *(const s16x8*)(xrow + kb * 32 + q * 8);
    s16x8 b0 = *(const s16x8*)(wb + (size_t)(kb * 2 + 0) * 512);
    s16x8 b1 = *(const s16x8*)(wb + (size_t)(kb * 2 + 1) * 512);
    acc0 = mfma16(a, b0, acc0);
    acc1 = mfma16(a, b1, acc1);
  }
#pragma unroll
  for (int kb = 8; kb < 24; kb++) {                   // recurrent part of K (512)
    s16x8 a  = ld16_llc(hrow + (kb - 8) * 32 + q * 8);
    s16x8 b0 = *(const s16x8*)(wb + (size_t)(kb * 2 + 0) * 512);
    s16x8 b1 = *(const s16x8*)(wb + (size_t)(kb * 2 + 1) * 512);
    acc0 = mfma16(a, b0, acc0);
    acc1 = mfma16(a, b1, acc1);
  }
  float* Ds = (float*)(smem + OFF_DS);
#pragma unroll
  for (int i = 0; i < 4; i++) {
    Ds[(row0 + q * 4 + i) * 33 + r]      = acc0[i];
    Ds[(row0 + q * 4 + i) * 33 + 16 + r] = acc1[i];
  }
  __syncthreads();
  const float* bs = (const float*)(smem + offB);
  float* Cs = (float*)(smem + offC);
  if (tid < 128) {
    int row = tid >> 1, j0 = (tid & 1) * 4;
    union { u16 h[4]; u64 qv; } pk;
#pragma unroll
    for (int i = 0; i < 4; i++) {
      int j = j0 + i;
      float vi = Ds[row * 33 + 0 + j]  + bs[0 + j];
      float vf = Ds[row * 33 + 8 + j]  + bs[8 + j];
      float vo = Ds[row * 33 + 16 + j] + bs[16 + j];
      float vc = Ds[row * 33 + 24 + j] + bs[24 + j];
      float I = sigm(vi), F = sigm(vf), O = sigm(vo), Ct = tanh_(vc);
      float Cn = F * Cs[row * 8 + j] + I * Ct;
      Cs[row * 8 + j] = Cn;
      pk.h[i] = f2bf(O * tanh_(Cn));
    }
    st8_llc(Hdst + (size_t)(g * 64 + row) * HID_ + c * 8 + j0, pk.qv);
  }
}

// Fused phase A: cell2(t) [x=Xt2, rec=Hr2=H1m, out=Hd2=H1b] concurrent with
// cell1(t+1) [x=Xt1, rec=Hr1=H(t), out=Hd1=Hb[t&1]]. Both x-parts are issued
// BEFORE the barrier poll (no recurrent dependency) to hide flag latency;
// the two recurrent LLC load streams are interleaved so their latencies overlap.
__device__ __forceinline__ void fusedA(char* smem, int* fl, int waitph,
                                       const u16* Xt2, const u16* Xt1,
                                       const u16* Hr2, const u16* Hr1,
                                       u16* Hd2, u16* Hd1,
                                       int g, int c, int w, int lane, int tid) {
  const int r = lane & 15, q = lane >> 4;
  const int row0 = w * 16;
  const size_t rb = (size_t)(g * 64 + row0 + r);
  const u16* x2 = Xt2 + rb * EMB_;
  const u16* x1 = Xt1 + rb * EMB_;
  const u16* wb3 = (const u16*)(smem + OFF_W3) + lane * 8;   // cell2 weights
  const u16* wb1 = (const u16*)(smem + OFF_W1) + lane * 8;   // cell1 weights
  f32x4 a2c0 = {0.f, 0.f, 0.f, 0.f}, a2c1 = {0.f, 0.f, 0.f, 0.f};
  f32x4 a1c0 = {0.f, 0.f, 0.f, 0.f}, a1c1 = {0.f, 0.f, 0.f, 0.f};
#pragma unroll
  for (int kb = 0; kb < 8; kb++) {                    // both x-parts, pre-barrier
    s16x8 a2 = *(const s16x8*)(x2 + kb * 32 + q * 8);
    s16x8 a1 = *(const s16x8*)(x1 + kb * 32 + q * 8);
    s16x8 b30 = *(const s16x8*)(wb3 + (size_t)(kb * 2 + 0) * 512);
    s16x8 b31 = *(const s16x8*)(wb3 + (size_t)(kb * 2 + 1) * 512);
    s16x8 b10 = *(const s16x8*)(wb1 + (size_t)(kb * 2 + 0) * 512);
    s16x8 b11 = *(const s16x8*)(wb1 + (size_t)(kb * 2 + 1) * 512);
    a2c0 = mfma16(a2, b30, a2c0);
    a2c1 = mfma16(a2, b31, a2c1);
    a1c0 = mfma16(a1, b10, a1c0);
    a1c1 = mfma16(a1, b11, a1c1);
  }
  // now wait for producers of H(t), H1m(t), and the WAR-safety of our stores
  waitbar(fl, waitph);
  const u16* h2 = Hr2 + rb * HID_;
  const u16* h1 = Hr1 + rb * HID_;
#pragma unroll
  for (int kb = 0; kb < 16; kb++) {                   // fused recurrent K (512 each)
    s16x8 a2 = ld16_llc(h2 + kb * 32 + q * 8);
    s16x8 a1 = ld16_llc(h1 + kb * 32 + q * 8);
    s16x8 b30 = *(const s16x8*)(wb3 + (size_t)((kb + 8) * 2 + 0) * 512);
    s16x8 b31 = *(const s16x8*)(wb3 + (size_t)((kb + 8) * 2 + 1) * 512);
    s16x8 b10 = *(const s16x8*)(wb1 + (size_t)((kb + 8) * 2 + 0) * 512);
    s16x8 b11 = *(const s16x8*)(wb1 + (size_t)((kb + 8) * 2 + 1) * 512);
    a2c0 = mfma16(a2, b30, a2c0);
    a2c1 = mfma16(a2, b31, a2c1);
    a1c0 = mfma16(a1, b10, a1c0);
    a1c1 = mfma16(a1, b11, a1c1);
  }
  float* D2 = (float*)(smem + OFF_DS);
  float* D1 = (float*)(smem + OFF_DS1);
#pragma unroll
  for (int i = 0; i < 4; i++) {
    D2[(row0 + q * 4 + i) * 33 + r]      = a2c0[i];
    D2[(row0 + q * 4 + i) * 33 + 16 + r] = a2c1[i];
    D1[(row0 + q * 4 + i) * 33 + r]      = a1c0[i];
    D1[(row0 + q * 4 + i) * 33 + 16 + r] = a1c1[i];
  }
  __syncthreads();
  // elementwise, all 256 threads: waves 0-1 -> cell2, waves 2-3 -> cell1
  {
    const int half = tid >> 7;            // wave-uniform
    const int t2 = tid & 127;
    const int row = t2 >> 1, j0 = (t2 & 1) * 4;
    const float* bs = (const float*)(smem + (half ? OFF_B1 : OFF_B3));
    float* Cs = (float*)(smem + (half ? OFF_C : OFF_C1));
    const float* Ds = half ? D1 : D2;
    u16* Hdst = half ? Hd1 : Hd2;
    union { u16 h[4]; u64 qv; } pk;
#pragma unroll
    for (int i = 0; i < 4; i++) {
      int j = j0 + i;
      float vi = Ds[row * 33 + 0 + j]  + bs[0 + j];
      float vf = Ds[row * 33 + 8 + j]  + bs[8 + j];
      float vo = Ds[row * 33 + 16 + j] + bs[16 + j];
      float vc = Ds[row * 33 + 24 + j] + bs[24 + j];
      float I = sigm(vi), F = sigm(vf), O = sigm(vo), Ct = tanh_(vc);
      float Cn = F * Cs[row * 8 + j] + I * Ct;
      Cs[row * 8 + j] = Cn;
      pk.h[i] = f2bf(O * tanh_(Cn));
    }
    st8_llc(Hdst + (size_t)(g * 64 + row) * HID_ + c * 8 + j0, pk.qv);
  }
}

// Phase B: H1m = sigmoid(Hnew@W_xh + H1old@W_hh + b_h), pair-split cols.
__device__ __forceinline__ void mix_phase(char* smem, const u16* Hnew, const u16* H1old,
                                          u16* H1m, int g, int c, int w, int lane, int tid) {
  const int r = lane & 15, q = lane >> 4;
  float* Ds = (float*)(smem + OFF_DS);
  if (w < 2) {
    int rbase = g * 64 + (c & 1) * 32 + w * 16 + r;
    const u16* h0 = Hnew + (size_t)rbase * HID_;
    const u16* h1 = H1old + (size_t)rbase * HID_;
    const u16* wb = (const u16*)(smem + OFF_W2) + lane * 8;
    f32x4 acc = {0.f, 0.f, 0.f, 0.f};
#pragma unroll
    for (int kb = 0; kb < 16; kb++) {
      s16x8 a = ld16_llc(h0 + kb * 32 + q * 8);
      s16x8 b = *(const s16x8*)(wb + (size_t)kb * 512);
      acc = mfma16(a, b, acc);
    }
#pragma unroll
    for (int kb = 16; kb < 32; kb++) {
      s16x8 a = ld16_llc(h1 + (kb - 16) * 32 + q * 8);
      s16x8 b = *(const s16x8*)(wb + (size_t)kb * 512);
      acc = mfma16(a, b, acc);
    }
#pragma unroll
    for (int i = 0; i < 4; i++)
      Ds[(w * 16 + q * 4 + i) * 17 + r] = acc[i];
  }
  __syncthreads();
  if (tid < 128) {
    const float* b2 = (const float*)(smem + OFF_B2);
    int row = tid >> 2, j0 = (tid & 3) * 4;
    union { u16 h[4]; u64 qv; } pk;
#pragma unroll
    for (int i = 0; i < 4; i++)
      pk.h[i] = f2bf(sigm(Ds[row * 17 + j0 + i] + b2[j0 + i]));
    st8_llc(H1m + (size_t)(g * 64 + (c & 1) * 32 + row) * HID_ + (c >> 1) * 16 + j0,
            pk.qv);
  }
}

__global__ __launch_bounds__(NTHR, 1) void lstm_pers(Params p) {
  extern __shared__ char smem[];
  const int tid = threadIdx.x;
  const int bi = blockIdx.x;
  const int w = tid >> 6, lane = tid & 63;
  const int g = bi >> 6, c = bi & 63;
  const int r = lane & 15, q = lane >> 4;
  (void)r; (void)q;

  int* fl = (int*)(p.ws + WS_FL) + g * 64 * 32;   // padded: one line per WG
  int* dn = (int*)(p.ws + WS_DONE);
  u16* Hb0 = (u16*)(p.ws + WS_HB0);
  u16* Hb1 = (u16*)(p.ws + WS_HB1);
  u16* H1b = (u16*)(p.ws + WS_H1);
  u16* H1m = (u16*)(p.ws + WS_HM);
  u16* Xe  = (u16*)(p.ws + WS_XE);

  // ---- one-time init: weights -> LDS (bf16, MFMA lane-order swizzle) ----
  {
    u16* w1 = (u16*)(smem + OFF_W1);
    u16* w3 = (u16*)(smem + OFF_W3);
    int gate = tid >> 6, kk8 = (tid >> 3) & 7, j = tid & 7;
    int cc = gate * 8 + j;          // col 0..31 (i0..7,f0..7,o0..7,c0..7)
    int n = cc >> 4, rr = cc & 15;
    int hid = c * 8 + j;
    for (int kk = kk8; kk < 768; kk += 8) {
      int kb = kk >> 5, q2 = (kk >> 3) & 3, e = kk & 7;
      size_t dst = ((size_t)(kb * 2 + n) * 64 + q2 * 16 + rr) * 8 + e;
      float s1 = (kk < 256) ? p.Wx[gate][(size_t)kk * HID_ + hid]
                            : p.Wh[gate][(size_t)(kk - 256) * HID_ + hid];
      float s3 = (kk < 256) ? p.Wx1[gate][(size_t)kk * HID_ + hid]
                            : p.Wh1[gate][(size_t)(kk - 256) * HID_ + hid];
      w1[dst] = f2bf(s1);
      w3[dst] = f2bf(s3);
    }
    {  // mix weights: every WG holds cols (c>>1)*16..+15 (pairs share)
      u16* w2 = (u16*)(smem + OFF_W2);
      int kk16 = tid >> 4, j2 = tid & 15;
      int hid2 = (c >> 1) * 16 + j2;
      for (int kk = kk16; kk < 1024; kk += 16) {
        int kb = kk >> 5, q2 = (kk >> 3) & 3, e = kk & 7;
        size_t dst = ((size_t)kb * 64 + q2 * 16 + j2) * 8 + e;
        float s = (kk < 512) ? p.Wxh[(size_t)kk * HID_ + hid2]
                             : p.Whh[(size_t)(kk - 512) * HID_ + hid2];
        w2[dst] = f2bf(s);
      }
      if (tid < 16) ((float*)(smem + OFF_B2))[tid] = p.bh[(c >> 1) * 16 + tid];
    }
    if (tid < 32) {
      int gt = tid >> 3, jj = tid & 7;
      ((float*)(smem + OFF_B1))[tid] = p.bg[gt][c * 8 + jj];
      ((float*)(smem + OFF_B3))[tid] = p.bg1[gt][c * 8 + jj];
    }
    // C / C1 state (fp32, LDS-resident, WG-local forever)
    float* Cs = (float*)(smem + OFF_C);
    float* C1s = (float*)(smem + OFF_C1);
    for (int it = 0; it < 2; it++) {
      int idx = tid + it * 256;
      int row = idx >> 3, j8 = idx & 7;
      float v = p.Cin[(size_t)(g * 64 + row) * HID_ + c * 8 + j8];
      Cs[row * 8 + j8] = v;
      C1s[row * 8 + j8] = v;
    }
  }
  // H / H1 state init (bf16 in ws, normal stores -> published by heavy barrier)
  // Convention: H(t) lives in Hb[(t+1)&1]; H(-1)=Hin in Hb0.
  for (int it = 0; it < 2; it++) {
    int idx = bi * 512 + tid + it * 256;
    u16 hv = f2bf(p.Hin[idx]);
    Hb0[idx] = hv;
    H1b[idx] = hv;
  }
  // Embedding gather, group-local: WG (g,c) fills Xe[t=4c..4c+3][g*64..+63][:]
  for (int tt = 0; tt < 4; tt++) {
    int t0 = c * 4 + tt;
    for (int pp = 0; pp < 16; pp++) {
      int b = g * 64 + w * 16 + pp;
      int tok = p.X[(size_t)b * Tt + t0];
      const float4* er = (const float4*)(p.E + (size_t)tok * EMB_);
      float4 v = er[lane];
      u16x4 u; u.x = f2bf(v.x); u.y = f2bf(v.y); u.z = f2bf(v.z); u.w = f2bf(v.w);
      *(u16x4*)(Xe + ((size_t)t0 * Bb + b) * EMB_ + lane * 4) = u;
    }
  }
  int ph = 0;
  groupbar_heavy(fl, c, ++ph);   // ph=1: publish init data

  // ---- prologue: cell1(0) then mix(0) ----
  cell_phase(smem, OFF_W1, OFF_B1, OFF_C, Xe, Hb0, Hb1, g, c, w, lane, tid);
  arrive(fl, c, ++ph);           // ph=2
  waitbar(fl, ph);
  mix_phase(smem, Hb1, H1b, H1m, g, c, w, lane, tid);
  arrive(fl, c, ++ph);           // ph=3

  // ---- steady state: 2 phases per timestep ----
  for (int t = 0; t < Tt - 1; t++) {
    const u16* Xt  = Xe + (size_t)t * Bb * EMB_;
    const u16* Xt1 = Xe + (size_t)(t + 1) * Bb * EMB_;
    u16* Hsrc = (t & 1) ? Hb0 : Hb1;    // H(t)   at Hb[(t+1)&1]
    u16* Hdst = (t & 1) ? Hb1 : Hb0;    // H(t+1) at Hb[t&1]

    // Phase A_t: cell2(t) || cell1(t+1); waits ph (mix(t) + all WGs past readers)
    fusedA(smem, fl, ph, Xt, Xt1, H1m, Hsrc, H1b, Hdst, g, c, w, lane, tid);
    arrive(fl, c, ++ph);

    // Phase B_t: mix(t+1) from H(t+1) and H1(t)
    waitbar(fl, ph);
    mix_phase(smem, Hdst, H1b, H1m, g, c, w, lane, tid);
    arrive(fl, c, ++ph);
  }

  // ---- epilogue: cell2(T-1) ----
  waitbar(fl, ph);
  {
    const u16* Xt = Xe + (size_t)(Tt - 1) * Bb * EMB_;
    cell_phase(smem, OFF_W3, OFF_B3, OFF_C1, Xt, H1m, H1b, g, c, w, lane, tid);
  }

  // ---- all-groups done (heavy: acquire-inv), then final GEMM with cached loads ----
  donebar(dn, bi);
  if (bi < 250) {
    const int n0 = bi * 128;
    u16* Wf = (u16*)smem;   // reuse weight LDS: [16 kb][8 nt][64 lane][8]
    for (int idx = tid; idx < 512 * 128; idx += NTHR) {
      int k = idx >> 7, nn2 = idx & 127;
      int nt = nn2 >> 4, rr = nn2 & 15;
      int kb = k >> 5, q2 = (k >> 3) & 3, e = k & 7;
      Wf[((size_t)(kb * 8 + nt) * 64 + q2 * 16 + rr) * 8 + e] =
          f2bf(p.Whq[(size_t)k * NCLS + n0 + nn2]);
    }
    float* bqs = (float*)(smem + OFF_C);
    if (tid < 128) bqs[tid] = p.bq[n0 + tid];
    __syncthreads();
    const int r2 = lane & 15, q2 = lane >> 4;
    for (int mt = 0; mt < 4; mt++) {
      int rowb = mt * 64 + w * 16;
      const u16* arow = H1b + (size_t)(rowb + r2) * HID_;
      f32x4 acc[8];
#pragma unroll
      for (int nt = 0; nt < 8; nt++) acc[nt] = (f32x4){0.f, 0.f, 0.f, 0.f};
      for (int kb = 0; kb < 16; kb++) {
        s16x8 a = *(const s16x8*)(arow + kb * 32 + q2 * 8);
#pragma unroll
        for (int nt = 0; nt < 8; nt++) {
          s16x8 b = *(const s16x8*)((const u16*)Wf + ((size_t)(kb * 8 + nt) * 64 + lane) * 8);
          acc[nt] = mfma16(a, b, acc[nt]);
        }
      }
#pragma unroll
      for (int nt = 0; nt < 8; nt++)
#pragma unroll
        for (int i = 0; i < 4; i++)
          p.out[(size_t)(rowb + q2 * 4 + i) * NCLS + n0 + nt * 16 + r2] =
              acc[nt][i] + bqs[nt * 16 + r2];
    }
  }
}

extern "C" void kernel_launch(void* const* d_in, const int* in_sizes, int n_in,
                              void* d_out, int out_size, void* d_ws, size_t ws_size,
                              hipStream_t stream) {
  (void)in_sizes; (void)n_in; (void)out_size; (void)ws_size;
  Params p;
  p.X   = (const int*)d_in[0];
  p.Hin = (const float*)d_in[1];
  p.Cin = (const float*)d_in[2];
  p.E   = (const float*)d_in[3];
  for (int gidx = 0; gidx < 4; gidx++) {   // gate order i,f,o,c
    int base = 4 + gidx * 6;
    p.Wx[gidx]  = (const float*)d_in[base + 0];
    p.Wh[gidx]  = (const float*)d_in[base + 1];
    p.bg[gidx]  = (const float*)d_in[base + 2];
    p.Wx1[gidx] = (const float*)d_in[base + 3];
    p.Wh1[gidx] = (const float*)d_in[base + 4];
    p.bg1[gidx] = (const float*)d_in[base + 5];
  }
  p.Wxh = (const float*)d_in[28];
  p.Whh = (const float*)d_in[29];
  p.bh  = (const float*)d_in[30];
  p.Whq = (const float*)d_in[31];
  p.bq  = (const float*)d_in[32];
  p.out = (float*)d_out;
  p.ws  = (char*)d_ws;

  hipFuncSetAttribute(reinterpret_cast<const void*>(lstm_pers),
                      hipFuncAttributeMaxDynamicSharedMemorySize, SMEM_BYTES);
  lstm_pers<<<dim3(NWG), dim3(NTHR), SMEM_BYTES, stream>>>(p);
}

// Round 2
// 4544.285 us; speedup vs baseline: 1.1792x; 1.0143x over previous
//
#include <hip/hip_runtime.h>
#include <cstdint>
#include <cstddef>

typedef unsigned short u16;
typedef unsigned long long u64;
typedef __attribute__((ext_vector_type(8))) short s16x8;
typedef __attribute__((ext_vector_type(4))) float f32x4;
typedef __attribute__((ext_vector_type(4))) unsigned short u16x4;

#define AGENT __HIP_MEMORY_SCOPE_AGENT

namespace {
constexpr int NWG  = 256;
constexpr int NTHR = 256;
constexpr int Bb   = 256;   // batch
constexpr int Tt   = 256;   // timesteps
constexpr int EMB_ = 256;
constexpr int HID_ = 512;
constexpr int NCLS = 32000;

// ---- LDS layout (bytes). B-operands stored in MFMA lane order:
//      elem addr = ((kb*NT + n)*64 + lane)*8 + e  -> ds_read_b128 lane-linear, 0 conflicts
constexpr int OFF_W1  = 0;        // cell1 [24 kb][2 n][64 lane][8] = 49152 B
constexpr int OFF_W3  = 49152;    // cell2, same shape
constexpr int OFF_W2  = 98304;    // mix   [32 kb][1 n][64][8]     = 32768 B
constexpr int OFF_DS  = 131072;   // cell2 gate scratch [64][33] f32 = 8448 B
constexpr int OFF_DS1 = 139520;   // cell1 gate scratch [64][33] f32 = 8448 B
constexpr int OFF_DSM = 147968;   // mix per-wave transpose 2 x [16][17] f32 = 2176 B
constexpr int OFF_C   = 150144;   // cell1 C state [64][8] f32 (bq reuse in final)
constexpr int OFF_C1  = 152192;   // cell2 C state
constexpr int OFF_B1  = 154240;
constexpr int OFF_B3  = 154368;
constexpr int OFF_B2  = 154496;
constexpr int SMEM_BYTES = 154560;            // 1 WG/CU

// ---- workspace layout (bytes) ----
constexpr size_t WS_FL   = 0;                          // 256 WGs x 128 B = 32 KB
constexpr size_t WS_DONE = 32768;                      // 256 int done flags (one-time)
constexpr size_t WS_HB0  = 33792;                      // H parity buffers [B][512] bf16
constexpr size_t WS_HB1  = WS_HB0 + (size_t)Bb * HID_ * 2;
constexpr size_t WS_H1   = WS_HB1 + (size_t)Bb * HID_ * 2;   // H1 state
constexpr size_t WS_HM   = WS_H1 + (size_t)Bb * HID_ * 2;    // H1mix
constexpr size_t WS_XE   = WS_HM + (size_t)Bb * HID_ * 2;    // Xe [T][B][EMB] bf16
}  // namespace

struct Params {
  const int* X; const float* Hin; const float* Cin; const float* E;
  const float* Wx[4];  const float* Wh[4];  const float* bg[4];   // cell 1 (i,f,o,c)
  const float* Wx1[4]; const float* Wh1[4]; const float* bg1[4];  // cell 2
  const float* Wxh; const float* Whh; const float* bh;
  const float* Whq; const float* bq;
  float* out; char* ws;
};

__device__ __forceinline__ u16 f2bf(float f) {
  union { float f; unsigned u; } v; v.f = f;
  unsigned r = v.u + 0x7FFFu + ((v.u >> 16) & 1u);
  return (u16)(r >> 16);
}
__device__ __forceinline__ float sigm(float x) { return 1.f / (1.f + __expf(-x)); }
__device__ __forceinline__ float tanh_(float x) {
  x = fminf(fmaxf(x, -10.f), 10.f);
  float e = __expf(-2.f * x);
  return (1.f - e) / (1.f + e);
}
__device__ __forceinline__ f32x4 mfma16(s16x8 a, s16x8 b, f32x4 c) {
  return __builtin_amdgcn_mfma_f32_16x16x32_bf16(a, b, c, 0, 0, 0);
}

// ---- LLC-coherent data movement: relaxed agent atomics bypass L1/L2 and are
// serviced at the memory-side Infinity Cache -> no wbl2/inv needed.
__device__ __forceinline__ void st8_llc(u16* p2, u64 v) {
  __hip_atomic_store((u64*)p2, v, __ATOMIC_RELAXED, AGENT);
}
__device__ __forceinline__ u64 ld8_llc(const u16* p2) {
  return __hip_atomic_load((const u64*)p2, __ATOMIC_RELAXED, AGENT);
}
__device__ __forceinline__ s16x8 ld16_llc(const u16* p2) {
  union { u64 q[2]; s16x8 v; } u;
  u.q[0] = ld8_llc(p2);
  u.q[1] = ld8_llc(p2 + 4);
  return u.v;
}

// Split barrier: arrive (after our stores drained by __syncthreads' vmcnt(0)) /
// waitbar (poll all 64 flags). Pre-wait work is queued before waitbar by callers.
__device__ __forceinline__ void arrive(int* fl, int slot, int ph) {
  __syncthreads();
  if (threadIdx.x == 0)
    __hip_atomic_store(&fl[slot * 32], ph, __ATOMIC_RELAXED, AGENT);
}
__device__ __forceinline__ void waitbar(int* fl, int ph) {
  if (threadIdx.x < 64) {
    for (;;) {
      int v = __hip_atomic_load(&fl[threadIdx.x * 32], __ATOMIC_RELAXED, AGENT);
      if (!__any(v < ph)) break;
      __builtin_amdgcn_s_sleep(1);
    }
  }
  __syncthreads();
  __builtin_amdgcn_fence(__ATOMIC_ACQUIRE, "workgroup");  // compiler/order barrier, cheap
}

// Heavy barrier (release store + agent acquire fence -> wbl2/inv). Used ONCE
// after init (publishes normal-stored Xe/H-init).
__device__ __forceinline__ void groupbar_heavy(int* fl, int slot, int ph) {
  __syncthreads();
  if (threadIdx.x == 0)
    __hip_atomic_store(&fl[slot * 32], ph, __ATOMIC_RELEASE, AGENT);
  if (threadIdx.x < 64) {
    for (;;) {
      int v = __hip_atomic_load(&fl[threadIdx.x * 32], __ATOMIC_RELAXED, AGENT);
      if (!__any(v < ph)) break;
      __builtin_amdgcn_s_sleep(1);
    }
  }
  __syncthreads();
  __builtin_amdgcn_fence(__ATOMIC_ACQUIRE, "agent");
}

// One-time all-grid done wait (before the final GEMM). Heavy on purpose: its
// acquire-inv lets the final GEMM use normal cached loads on H1b.
__device__ __forceinline__ void donebar(int* dn, int bi) {
  __syncthreads();
  if (threadIdx.x == 0)
    __hip_atomic_store(&dn[bi], 1, __ATOMIC_RELEASE, AGENT);
  for (;;) {
    int v = __hip_atomic_load(&dn[threadIdx.x], __ATOMIC_RELAXED, AGENT);
    if (!__any(v < 1)) break;
    __builtin_amdgcn_s_sleep(1);
  }
  __syncthreads();
  __builtin_amdgcn_fence(__ATOMIC_ACQUIRE, "agent");
}

// Single-cell phase (prologue cell1(0) only; 4 waves, full syncthreads handoff).
__device__ __forceinline__ void cell_phase(char* smem, int offW, int offB, int offC,
                                           const u16* Xt, const u16* Hrec, u16* Hdst,
                                           int g, int c, int w, int lane, int tid) {
  const int r = lane & 15, q = lane >> 4;
  const int row0 = w * 16;
  const u16* xrow = Xt + (size_t)(g * 64 + row0 + r) * EMB_;
  const u16* hrow = Hrec + (size_t)(g * 64 + row0 + r) * HID_;
  const u16* wb = (const u16*)(smem + offW) + lane * 8;
  f32x4 acc0 = {0.f, 0.f, 0.f, 0.f}, acc1 = {0.f, 0.f, 0.f, 0.f};
#pragma unroll
  for (int kb = 0; kb < 8; kb++) {                    // x_t part of K (256)
    s16x8 a  = *(const s16x8*)(xrow + kb * 32 + q * 8);
    s16x8 b0 = *(const s16x8*)(wb + (size_t)(kb * 2 + 0) * 512);
    s16x8 b1 = *(const s16x8*)(wb + (size_t)(kb * 2 + 1) * 512);
    acc0 = mfma16(a, b0, acc0);
    acc1 = mfma16(a, b1, acc1);
  }
  s16x8 ha[16];
#pragma unroll
  for (int kb = 0; kb < 16; kb++) ha[kb] = ld16_llc(hrow + kb * 32 + q * 8);
#pragma unroll
  for (int kb = 0; kb < 16; kb++) {                   // recurrent part of K (512)
    s16x8 b0 = *(const s16x8*)(wb + (size_t)((kb + 8) * 2 + 0) * 512);
    s16x8 b1 = *(const s16x8*)(wb + (size_t)((kb + 8) * 2 + 1) * 512);
    acc0 = mfma16(ha[kb], b0, acc0);
    acc1 = mfma16(ha[kb], b1, acc1);
  }
  float* Ds = (float*)(smem + OFF_DS);
#pragma unroll
  for (int i = 0; i < 4; i++) {
    Ds[(row0 + q * 4 + i) * 33 + r]      = acc0[i];
    Ds[(row0 + q * 4 + i) * 33 + 16 + r] = acc1[i];
  }
  __syncthreads();
  const float* bs = (const float*)(smem + offB);
  float* Cs = (float*)(smem + offC);
  if (tid < 128) {
    int row = tid >> 1, j0 = (tid & 1) * 4;
    union { u16 h[4]; u64 qv; } pk;
#pragma unroll
    for (int i = 0; i < 4; i++) {
      int j = j0 + i;
      float vi = Ds[row * 33 + 0 + j]  + bs[0 + j];
      float vf = Ds[row * 33 + 8 + j]  + bs[8 + j];
      float vo = Ds[row * 33 + 16 + j] + bs[16 + j];
      float vc = Ds[row * 33 + 24 + j] + bs[24 + j];
      float I = sigm(vi), F = sigm(vf), O = sigm(vo), Ct = tanh_(vc);
      float Cn = F * Cs[row * 8 + j] + I * Ct;
      Cs[row * 8 + j] = Cn;
      pk.h[i] = f2bf(O * tanh_(Cn));
    }
    st8_llc(Hdst + (size_t)(g * 64 + row) * HID_ + c * 8 + j0, pk.qv);
  }
}

// cell1 on waves 2-3 only: full gate GEMM + elementwise + H-store, no barrier.
// Wave wv ({0,1} = tid>>6 - 2) owns rows wv*32..+31; scratch handoff is
// intra-wave (lgkmcnt only). Runs entirely PRE-wait inside phase B.
__device__ __forceinline__ void cell1_w23(char* smem, const u16* Xt, const u16* Hrec,
                                          u16* Hdst, int g, int c, int lane, int tid) {
  const int wv = (tid >> 6) - 2;
  const int r = lane & 15, q = lane >> 4;
  const u16* wb1 = (const u16*)(smem + OFF_W1) + lane * 8;
  float* D1 = (float*)(smem + OFF_DS1);
#pragma unroll
  for (int blk = 0; blk < 2; blk++) {
    const int rb = wv * 32 + blk * 16;
    const u16* xrow = Xt + (size_t)(g * 64 + rb + r) * EMB_;
    const u16* hrow = Hrec + (size_t)(g * 64 + rb + r) * HID_;
    s16x8 xa[8];
#pragma unroll
    for (int kb = 0; kb < 8; kb++) xa[kb] = *(const s16x8*)(xrow + kb * 32 + q * 8);
    s16x8 hh[16];
#pragma unroll
    for (int kb = 0; kb < 16; kb++) hh[kb] = ld16_llc(hrow + kb * 32 + q * 8);
    f32x4 a0 = {0.f, 0.f, 0.f, 0.f}, a1 = {0.f, 0.f, 0.f, 0.f};
#pragma unroll
    for (int kb = 0; kb < 8; kb++) {
      a0 = mfma16(xa[kb], *(const s16x8*)(wb1 + (size_t)(kb * 2 + 0) * 512), a0);
      a1 = mfma16(xa[kb], *(const s16x8*)(wb1 + (size_t)(kb * 2 + 1) * 512), a1);
    }
#pragma unroll
    for (int kb = 0; kb < 16; kb++) {
      a0 = mfma16(hh[kb], *(const s16x8*)(wb1 + (size_t)((kb + 8) * 2 + 0) * 512), a0);
      a1 = mfma16(hh[kb], *(const s16x8*)(wb1 + (size_t)((kb + 8) * 2 + 1) * 512), a1);
    }
#pragma unroll
    for (int i = 0; i < 4; i++) {
      D1[(rb + q * 4 + i) * 33 + r]      = a0[i];
      D1[(rb + q * 4 + i) * 33 + 16 + r] = a1[i];
    }
  }
  // elementwise: wave wv reads rows wv*32..+31, which it wrote (intra-wave)
  const float* bs = (const float*)(smem + OFF_B1);
  float* Cs = (float*)(smem + OFF_C);
  int t2 = tid - 128;
  int row = t2 >> 1, j0 = (t2 & 1) * 4;
  union { u16 h[4]; u64 qv; } pk;
#pragma unroll
  for (int i = 0; i < 4; i++) {
    int j = j0 + i;
    float vi = D1[row * 33 + 0 + j]  + bs[0 + j];
    float vf = D1[row * 33 + 8 + j]  + bs[8 + j];
    float vo = D1[row * 33 + 16 + j] + bs[16 + j];
    float vc = D1[row * 33 + 24 + j] + bs[24 + j];
    float I = sigm(vi), F = sigm(vf), O = sigm(vo), Ct = tanh_(vc);
    float Cn = F * Cs[row * 8 + j] + I * Ct;
    Cs[row * 8 + j] = Cn;
    pk.h[i] = f2bf(O * tanh_(Cn));
  }
  st8_llc(Hdst + (size_t)(g * 64 + row) * HID_ + c * 8 + j0, pk.qv);
}

// mix part 1 (pre-wait): acc = H(t+1) @ W_xh  (waves 0-1 only)
__device__ __forceinline__ f32x4 mix_part1(char* smem, const u16* Hnew, int g, int c,
                                           int w, int lane) {
  const int r = lane & 15, q = lane >> 4;
  int rbase = g * 64 + (c & 1) * 32 + w * 16 + r;
  const u16* h0 = Hnew + (size_t)rbase * HID_;
  const u16* wb = (const u16*)(smem + OFF_W2) + lane * 8;
  s16x8 ha[16];
#pragma unroll
  for (int kb = 0; kb < 16; kb++) ha[kb] = ld16_llc(h0 + kb * 32 + q * 8);
  f32x4 acc = {0.f, 0.f, 0.f, 0.f};
#pragma unroll
  for (int kb = 0; kb < 16; kb++)
    acc = mfma16(ha[kb], *(const s16x8*)(wb + (size_t)kb * 512), acc);
  return acc;
}

// mix part 2 (post-wait): acc += H1(t) @ W_hh; sigmoid; store H1m.
// Output transpose via per-wave private LDS (intra-wave, no barrier).
__device__ __forceinline__ void mix_part2(char* smem, f32x4 acc, const u16* H1old,
                                          u16* H1m, int g, int c, int w, int lane) {
  const int r = lane & 15, q = lane >> 4;
  int rbase = g * 64 + (c & 1) * 32 + w * 16 + r;
  const u16* h1 = H1old + (size_t)rbase * HID_;
  const u16* wb = (const u16*)(smem + OFF_W2) + lane * 8;
  s16x8 hb[16];
#pragma unroll
  for (int kb = 0; kb < 16; kb++) hb[kb] = ld16_llc(h1 + kb * 32 + q * 8);
#pragma unroll
  for (int kb = 0; kb < 16; kb++)
    acc = mfma16(hb[kb], *(const s16x8*)(wb + (size_t)(16 + kb) * 512), acc);
  float* Dm = (float*)(smem + OFF_DSM) + (size_t)w * 16 * 17;
#pragma unroll
  for (int i = 0; i < 4; i++) Dm[(q * 4 + i) * 17 + r] = acc[i];
  const float* b2 = (const float*)(smem + OFF_B2);
  int row2 = lane >> 2, j0 = (lane & 3) * 4;
  union { u16 h[4]; u64 qv; } pk;
#pragma unroll
  for (int i = 0; i < 4; i++)
    pk.h[i] = f2bf(sigm(Dm[row2 * 17 + j0 + i] + b2[j0 + i]));
  st8_llc(H1m + (size_t)(g * 64 + (c & 1) * 32 + w * 16 + row2) * HID_ + (c >> 1) * 16 + j0,
          pk.qv);
}

__global__ __launch_bounds__(NTHR, 1) void lstm_pers(Params p) {
  extern __shared__ char smem[];
  const int tid = threadIdx.x;
  const int bi = blockIdx.x;
  const int w = tid >> 6, lane = tid & 63;
  const int g = bi >> 6, c = bi & 63;
  const int r = lane & 15, q = lane >> 4;

  int* fl = (int*)(p.ws + WS_FL) + g * 64 * 32;   // padded: one line per WG
  int* dn = (int*)(p.ws + WS_DONE);
  u16* Hb0 = (u16*)(p.ws + WS_HB0);
  u16* Hb1 = (u16*)(p.ws + WS_HB1);
  u16* H1b = (u16*)(p.ws + WS_H1);
  u16* H1m = (u16*)(p.ws + WS_HM);
  u16* Xe  = (u16*)(p.ws + WS_XE);

  // ---- one-time init: weights -> LDS (bf16, MFMA lane-order swizzle) ----
  {
    u16* w1 = (u16*)(smem + OFF_W1);
    u16* w3 = (u16*)(smem + OFF_W3);
    int gate = tid >> 6, kk8 = (tid >> 3) & 7, j = tid & 7;
    int cc = gate * 8 + j;          // col 0..31 (i0..7,f0..7,o0..7,c0..7)
    int n = cc >> 4, rr = cc & 15;
    int hid = c * 8 + j;
    for (int kk = kk8; kk < 768; kk += 8) {
      int kb = kk >> 5, q2 = (kk >> 3) & 3, e = kk & 7;
      size_t dst = ((size_t)(kb * 2 + n) * 64 + q2 * 16 + rr) * 8 + e;
      float s1 = (kk < 256) ? p.Wx[gate][(size_t)kk * HID_ + hid]
                            : p.Wh[gate][(size_t)(kk - 256) * HID_ + hid];
      float s3 = (kk < 256) ? p.Wx1[gate][(size_t)kk * HID_ + hid]
                            : p.Wh1[gate][(size_t)(kk - 256) * HID_ + hid];
      w1[dst] = f2bf(s1);
      w3[dst] = f2bf(s3);
    }
    {  // mix weights: every WG holds cols (c>>1)*16..+15 (pairs share)
      u16* w2 = (u16*)(smem + OFF_W2);
      int kk16 = tid >> 4, j2 = tid & 15;
      int hid2 = (c >> 1) * 16 + j2;
      for (int kk = kk16; kk < 1024; kk += 16) {
        int kb = kk >> 5, q2 = (kk >> 3) & 3, e = kk & 7;
        size_t dst = ((size_t)kb * 64 + q2 * 16 + j2) * 8 + e;
        float s = (kk < 512) ? p.Wxh[(size_t)kk * HID_ + hid2]
                             : p.Whh[(size_t)(kk - 512) * HID_ + hid2];
        w2[dst] = f2bf(s);
      }
      if (tid < 16) ((float*)(smem + OFF_B2))[tid] = p.bh[(c >> 1) * 16 + tid];
    }
    if (tid < 32) {
      int gt = tid >> 3, jj = tid & 7;
      ((float*)(smem + OFF_B1))[tid] = p.bg[gt][c * 8 + jj];
      ((float*)(smem + OFF_B3))[tid] = p.bg1[gt][c * 8 + jj];
    }
    // C / C1 state (fp32, LDS-resident, WG-local forever)
    float* Cs = (float*)(smem + OFF_C);
    float* C1s = (float*)(smem + OFF_C1);
    for (int it = 0; it < 2; it++) {
      int idx = tid + it * 256;
      int row = idx >> 3, j8 = idx & 7;
      float v = p.Cin[(size_t)(g * 64 + row) * HID_ + c * 8 + j8];
      Cs[row * 8 + j8] = v;
      C1s[row * 8 + j8] = v;
    }
  }
  // H / H1 state init (bf16 in ws, normal stores -> published by heavy barrier)
  // Convention: H(t) lives in Hb[t&1]; H(-1)=Hin in Hb1.
  for (int it = 0; it < 2; it++) {
    int idx = bi * 512 + tid + it * 256;
    u16 hv = f2bf(p.Hin[idx]);
    Hb1[idx] = hv;
    H1b[idx] = hv;
  }
  // Embedding gather, group-local: WG (g,c) fills Xe[t=4c..4c+3][g*64..+63][:]
  for (int tt = 0; tt < 4; tt++) {
    int t0 = c * 4 + tt;
    for (int pp = 0; pp < 16; pp++) {
      int b = g * 64 + w * 16 + pp;
      int tok = p.X[(size_t)b * Tt + t0];
      const float4* er = (const float4*)(p.E + (size_t)tok * EMB_);
      float4 v = er[lane];
      u16x4 u; u.x = f2bf(v.x); u.y = f2bf(v.y); u.z = f2bf(v.z); u.w = f2bf(v.w);
      *(u16x4*)(Xe + ((size_t)t0 * Bb + b) * EMB_ + lane * 4) = u;
    }
  }
  int ph = 0;
  groupbar_heavy(fl, c, ++ph);   // ph=1: publish init data

  // ---- P0: cell1(0): H(-1)=Hb1 -> H(0)=Hb0 ----
  cell_phase(smem, OFF_W1, OFF_B1, OFF_C, Xe, Hb1, Hb0, g, c, w, lane, tid);
  arrive(fl, c, ++ph);           // ph=2

  // ---- P1: mix(0) [waves 0-1] + cell1(1) [waves 2-3] ----
  waitbar(fl, ph);
  if (w < 2) {
    f32x4 macc = mix_part1(smem, Hb0, g, c, w, lane);   // H(0) @ W_xh
    mix_part2(smem, macc, H1b, H1m, g, c, w, lane);     // + H1(-1) @ W_hh
  } else {
    cell1_w23(smem, Xe + (size_t)1 * Bb * EMB_, Hb0, Hb1, g, c, lane, tid);  // H(0)->H(1)
  }
  arrive(fl, c, ++ph);           // ph=3

  // ---- steady state: 2 thin phases per timestep ----
  for (int t = 0; t < Tt - 1; t++) {
    const u16* Xt = Xe + (size_t)t * Bb * EMB_;
    // ---------- Phase A_t: cell2(t) ----------
    {
      const u16* wb3 = (const u16*)(smem + OFF_W3) + lane * 8;
      const u16* xrow = Xt + (size_t)(g * 64 + w * 16 + r) * EMB_;
      f32x4 acc0 = {0.f, 0.f, 0.f, 0.f}, acc1 = {0.f, 0.f, 0.f, 0.f};
      s16x8 xa[8];
#pragma unroll
      for (int kb = 0; kb < 8; kb++) xa[kb] = *(const s16x8*)(xrow + kb * 32 + q * 8);
#pragma unroll
      for (int kb = 0; kb < 8; kb++) {     // x-part pre-wait
        acc0 = mfma16(xa[kb], *(const s16x8*)(wb3 + (size_t)(kb * 2 + 0) * 512), acc0);
        acc1 = mfma16(xa[kb], *(const s16x8*)(wb3 + (size_t)(kb * 2 + 1) * 512), acc1);
      }
      waitbar(fl, ph);                     // need H1m(t) from B_{t-1}
      const u16* hrow = H1m + (size_t)(g * 64 + w * 16 + r) * HID_;
      s16x8 ha[16];
#pragma unroll
      for (int kb = 0; kb < 16; kb++) ha[kb] = ld16_llc(hrow + kb * 32 + q * 8);
#pragma unroll
      for (int kb = 0; kb < 16; kb++) {
        acc0 = mfma16(ha[kb], *(const s16x8*)(wb3 + (size_t)((kb + 8) * 2 + 0) * 512), acc0);
        acc1 = mfma16(ha[kb], *(const s16x8*)(wb3 + (size_t)((kb + 8) * 2 + 1) * 512), acc1);
      }
      float* Ds = (float*)(smem + OFF_DS);
#pragma unroll
      for (int i = 0; i < 4; i++) {
        Ds[(w * 16 + q * 4 + i) * 33 + r]      = acc0[i];
        Ds[(w * 16 + q * 4 + i) * 33 + 16 + r] = acc1[i];
      }
      __syncthreads();
      if (tid < 128) {
        const float* bs = (const float*)(smem + OFF_B3);
        float* Cs = (float*)(smem + OFF_C1);
        int row = tid >> 1, j0 = (tid & 1) * 4;
        union { u16 h[4]; u64 qv; } pk;
#pragma unroll
        for (int i = 0; i < 4; i++) {
          int j = j0 + i;
          float vi = Ds[row * 33 + 0 + j]  + bs[0 + j];
          float vf = Ds[row * 33 + 8 + j]  + bs[8 + j];
          float vo = Ds[row * 33 + 16 + j] + bs[16 + j];
          float vc = Ds[row * 33 + 24 + j] + bs[24 + j];
          float I = sigm(vi), F = sigm(vf), O = sigm(vo), Ct = tanh_(vc);
          float Cn = F * Cs[row * 8 + j] + I * Ct;
          Cs[row * 8 + j] = Cn;
          pk.h[i] = f2bf(O * tanh_(Cn));
        }
        st8_llc(H1b + (size_t)(g * 64 + row) * HID_ + c * 8 + j0, pk.qv);
      }
      arrive(fl, c, ++ph);
    }
    // ---------- Phase B_t: mix(t+1) [w 0-1] + cell1(t+2) [w 2-3, pre-wait] ----------
    {
      const u16* Hnew = (t & 1) ? Hb0 : Hb1;   // H(t+1)
      u16* Hdst1      = (t & 1) ? Hb1 : Hb0;   // H(t+2)
      f32x4 macc = {0.f, 0.f, 0.f, 0.f};
      if (w < 2) {
        macc = mix_part1(smem, Hnew, g, c, w, lane);        // pre-wait half
      } else if (t + 2 < Tt) {
        cell1_w23(smem, Xe + (size_t)(t + 2) * Bb * EMB_, Hnew, Hdst1, g, c, lane, tid);
      }
      waitbar(fl, ph);                       // need H1(t) from A_t
      if (w < 2) mix_part2(smem, macc, H1b, H1m, g, c, w, lane);
      arrive(fl, c, ++ph);
    }
  }

  // ---- epilogue: cell2(255) ----
  {
    const u16* Xt = Xe + (size_t)(Tt - 1) * Bb * EMB_;
    const u16* wb3 = (const u16*)(smem + OFF_W3) + lane * 8;
    const u16* xrow = Xt + (size_t)(g * 64 + w * 16 + r) * EMB_;
    f32x4 acc0 = {0.f, 0.f, 0.f, 0.f}, acc1 = {0.f, 0.f, 0.f, 0.f};
    s16x8 xa[8];
#pragma unroll
    for (int kb = 0; kb < 8; kb++) xa[kb] = *(const s16x8*)(xrow + kb * 32 + q * 8);
#pragma unroll
    for (int kb = 0; kb < 8; kb++) {
      acc0 = mfma16(xa[kb], *(const s16x8*)(wb3 + (size_t)(kb * 2 + 0) * 512), acc0);
      acc1 = mfma16(xa[kb], *(const s16x8*)(wb3 + (size_t)(kb * 2 + 1) * 512), acc1);
    }
    waitbar(fl, ph);                         // mix(255) from B_254
    const u16* hrow = H1m + (size_t)(g * 64 + w * 16 + r) * HID_;
    s16x8 ha[16];
#pragma unroll
    for (int kb = 0; kb < 16; kb++) ha[kb] = ld16_llc(hrow + kb * 32 + q * 8);
#pragma unroll
    for (int kb = 0; kb < 16; kb++) {
      acc0 = mfma16(ha[kb], *(const s16x8*)(wb3 + (size_t)((kb + 8) * 2 + 0) * 512), acc0);
      acc1 = mfma16(ha[kb], *(const s16x8*)(wb3 + (size_t)((kb + 8) * 2 + 1) * 512), acc1);
    }
    float* Ds = (float*)(smem + OFF_DS);
#pragma unroll
    for (int i = 0; i < 4; i++) {
      Ds[(w * 16 + q * 4 + i) * 33 + r]      = acc0[i];
      Ds[(w * 16 + q * 4 + i) * 33 + 16 + r] = acc1[i];
    }
    __syncthreads();
    if (tid < 128) {
      const float* bs = (const float*)(smem + OFF_B3);
      float* Cs = (float*)(smem + OFF_C1);
      int row = tid >> 1, j0 = (tid & 1) * 4;
      union { u16 h[4]; u64 qv; } pk;
#pragma unroll
      for (int i = 0; i < 4; i++) {
        int j = j0 + i;
        float vi = Ds[row * 33 + 0 + j]  + bs[0 + j];
        float vf = Ds[row * 33 + 8 + j]  + bs[8 + j];
        float vo = Ds[row * 33 + 16 + j] + bs[16 + j];
        float vc = Ds[row * 33 + 24 + j] + bs[24 + j];
        float I = sigm(vi), F = sigm(vf), O = sigm(vo), Ct = tanh_(vc);
        float Cn = F * Cs[row * 8 + j] + I * Ct;
        Cs[row * 8 + j] = Cn;
        pk.h[i] = f2bf(O * tanh_(Cn));
      }
      st8_llc(H1b + (size_t)(g * 64 + row) * HID_ + c * 8 + j0, pk.qv);
    }
  }

  // ---- all-groups done (heavy: acquire-inv), then final GEMM with cached loads ----
  donebar(dn, bi);
  if (bi < 250) {
    const int n0 = bi * 128;
    u16* Wf = (u16*)smem;   // reuse weight LDS: [16 kb][8 nt][64 lane][8]
    for (int idx = tid; idx < 512 * 128; idx += NTHR) {
      int k = idx >> 7, nn2 = idx & 127;
      int nt = nn2 >> 4, rr = nn2 & 15;
      int kb = k >> 5, q2 = (k >> 3) & 3, e = k & 7;
      Wf[((size_t)(kb * 8 + nt) * 64 + q2 * 16 + rr) * 8 + e] =
          f2bf(p.Whq[(size_t)k * NCLS + n0 + nn2]);
    }
    float* bqs = (float*)(smem + OFF_C);
    if (tid < 128) bqs[tid] = p.bq[n0 + tid];
    __syncthreads();
    const int r2 = lane & 15, q2 = lane >> 4;
    for (int mt = 0; mt < 4; mt++) {
      int rowb = mt * 64 + w * 16;
      const u16* arow = H1b + (size_t)(rowb + r2) * HID_;
      f32x4 acc[8];
#pragma unroll
      for (int nt = 0; nt < 8; nt++) acc[nt] = (f32x4){0.f, 0.f, 0.f, 0.f};
      for (int kb = 0; kb < 16; kb++) {
        s16x8 a = *(const s16x8*)(arow + kb * 32 + q2 * 8);
#pragma unroll
        for (int nt = 0; nt < 8; nt++) {
          s16x8 b = *(const s16x8*)((const u16*)Wf + ((size_t)(kb * 8 + nt) * 64 + lane) * 8);
          acc[nt] = mfma16(a, b, acc[nt]);
        }
      }
#pragma unroll
      for (int nt = 0; nt < 8; nt++)
#pragma unroll
        for (int i = 0; i < 4; i++)
          p.out[(size_t)(rowb + q2 * 4 + i) * NCLS + n0 + nt * 16 + r2] =
              acc[nt][i] + bqs[nt * 16 + r2];
    }
  }
}

extern "C" void kernel_launch(void* const* d_in, const int* in_sizes, int n_in,
                              void* d_out, int out_size, void* d_ws, size_t ws_size,
                              hipStream_t stream) {
  (void)in_sizes; (void)n_in; (void)out_size; (void)ws_size;
  Params p;
  p.X   = (const int*)d_in[0];
  p.Hin = (const float*)d_in[1];
  p.Cin = (const float*)d_in[2];
  p.E   = (const float*)d_in[3];
  for (int gidx = 0; gidx < 4; gidx++) {   // gate order i,f,o,c
    int base = 4 + gidx * 6;
    p.Wx[gidx]  = (const float*)d_in[base + 0];
    p.Wh[gidx]  = (const float*)d_in[base + 1];
    p.bg[gidx]  = (const float*)d_in[base + 2];
    p.Wx1[gidx] = (const float*)d_in[base + 3];
    p.Wh1[gidx] = (const float*)d_in[base + 4];
    p.bg1[gidx] = (const float*)d_in[base + 5];
  }
  p.Wxh = (const float*)d_in[28];
  p.Whh = (const float*)d_in[29];
  p.bh  = (const float*)d_in[30];
  p.Whq = (const float*)d_in[31];
  p.bq  = (const float*)d_in[32];
  p.out = (float*)d_out;
  p.ws  = (char*)d_ws;

  hipFuncSetAttribute(reinterpret_cast<const void*>(lstm_pers),
                      hipFuncAttributeMaxDynamicSharedMemorySize, SMEM_BYTES);
  lstm_pers<<<dim3(NWG), dim3(NTHR), SMEM_BYTES, stream>>>(p);
}